// Round 6
// baseline (471.149 us; speedup 1.0000x reference)
//
#include <hip/hip_runtime.h>

#define BB 16
#define NT 2048
#define NC 2048
#define DIM 256
#define INDIM 128

typedef unsigned short u16;
typedef __bf16 bfx8 __attribute__((ext_vector_type(8)));
typedef __bf16 bfx8a __attribute__((ext_vector_type(8), aligned(8)));
typedef float f32x4 __attribute__((ext_vector_type(4)));

__device__ __forceinline__ u16 f2bf(float f) {
    union { float f; unsigned u; } v; v.f = f;
    return (u16)((v.u + 0x7FFFu + ((v.u >> 16) & 1u)) >> 16);
}

#define MFMA16(a, b, c) __builtin_amdgcn_mfma_f32_16x16x32_bf16((a), (b), (c), 0, 0, 0)

// ---------------- converts ----------------

// all six weight transposes in ONE launch: w[K][256] fp32 -> wt[256][K] bf16
__global__ void cvt_w_all(const float* __restrict__ w0, const float* __restrict__ w1,
                          const float* __restrict__ w2, const float* __restrict__ w3,
                          const float* __restrict__ w4, const float* __restrict__ w5,
                          u16* __restrict__ o0, u16* __restrict__ o1, u16* __restrict__ o2,
                          u16* __restrict__ o3, u16* __restrict__ o4, u16* __restrict__ o5) {
    int bx = blockIdx.x;
    const float* src; u16* dst; int K, base;
    if (bx < 128)       { src = w0; dst = o0; K = 128; base = 0; }
    else if (bx < 384)  { src = w1; dst = o1; K = 256; base = 128; }
    else if (bx < 640)  { src = w2; dst = o2; K = 256; base = 384; }
    else if (bx < 768)  { src = w3; dst = o3; K = 128; base = 640; }
    else if (bx < 1024) { src = w4; dst = o4; K = 256; base = 768; }
    else                { src = w5; dst = o5; K = 256; base = 1024; }
    int idx = (bx - base) * 256 + threadIdx.x;
    int n = idx / K, k = idx - n * K;
    dst[idx] = f2bf(src[k * 256 + n]);
}

// r [B][NC][DIM] fp32 -> rt [B][DIM][NC] bf16
__global__ void cvt_rt_kernel(const float* __restrict__ r, u16* __restrict__ rt) {
    __shared__ u16 tile[32][33];
    int b = blockIdx.z;
    int c0 = blockIdx.x * 32, d0 = blockIdx.y * 32;
    int tx = threadIdx.x, ty = threadIdx.y; // (32, 8)
    const float* rb = r + (size_t)b * NC * DIM;
#pragma unroll
    for (int i = 0; i < 4; i++) {
        int c = c0 + ty + i * 8;
        tile[ty + i * 8][tx] = f2bf(rb[(size_t)c * DIM + d0 + tx]);
    }
    __syncthreads();
    u16* rtb = rt + (size_t)b * DIM * NC;
#pragma unroll
    for (int i = 0; i < 4; i++) {
        int d = d0 + ty + i * 8;
        rtb[(size_t)d * NC + c0 + tx] = tile[tx][ty + i * 8];
    }
}

// ---------------- fused MLP layer: C[M,256] = act(A[M,K] @ Wt[256,K]^T + b) --------------

template <int K, bool RELU, bool CVTIN>
__global__ __launch_bounds__(256) void mlp_gemm(const void* __restrict__ Aq, const void* __restrict__ Ak,
                                                const u16* __restrict__ Wq, const u16* __restrict__ Wk,
                                                const float* __restrict__ bq, const float* __restrict__ bk,
                                                u16* __restrict__ Cq, u16* __restrict__ Ck) {
    constexpr int ROWB = K * 2;          // A-tile row bytes (bf16)
    constexpr int NCH = K / 16;          // 16B chunks per thread
    __shared__ __align__(16) u16 at[128 * K];

    int tid = threadIdx.x, lane = tid & 63, w = tid >> 6;
    int lr = lane & 15, lg = lane >> 4;
    int m0 = blockIdx.x * 128;
    bool isq = (blockIdx.y == 0);
    const u16* Wt = isq ? Wq : Wk;
    const float* bias = isq ? bq : bk;
    u16* C = isq ? Cq : Ck;

    if (CVTIN) {
        const float* A = (const float*)(isq ? Aq : Ak) + (size_t)m0 * K;
#pragma unroll
        for (int j = 0; j < NCH; j++) {
            int bo = tid * (NCH * 16) + j * 16;
            int row = bo >> 8;                        // K=128: 256 B rows
            int ir = bo & (ROWB - 1);
            const float* src = A + (size_t)row * K + (ir >> 1);
            float4 f0 = *reinterpret_cast<const float4*>(src);
            float4 f1 = *reinterpret_cast<const float4*>(src + 4);
            union { u16 u[8]; uint4 v; } pk;
            {
                __bf16 h;
                h = (__bf16)f0.x; pk.u[0] = *(u16*)&h;
                h = (__bf16)f0.y; pk.u[1] = *(u16*)&h;
                h = (__bf16)f0.z; pk.u[2] = *(u16*)&h;
                h = (__bf16)f0.w; pk.u[3] = *(u16*)&h;
                h = (__bf16)f1.x; pk.u[4] = *(u16*)&h;
                h = (__bf16)f1.y; pk.u[5] = *(u16*)&h;
                h = (__bf16)f1.z; pk.u[6] = *(u16*)&h;
                h = (__bf16)f1.w; pk.u[7] = *(u16*)&h;
            }
            int dst = row * ROWB + (ir ^ ((row & 7) << 4));
            *reinterpret_cast<uint4*>((char*)at + dst) = pk.v;
        }
    } else {
        const char* A = (const char*)((const u16*)(isq ? Aq : Ak) + (size_t)m0 * K);
#pragma unroll
        for (int j = 0; j < NCH; j++) {
            int bo = j * 4096 + tid * 16;
            int row = bo >> 9;                        // K=256: 512 B rows
            int ir = bo & (ROWB - 1);
            int sir = ir ^ ((row & 7) << 4);
            __builtin_amdgcn_global_load_lds(
                (const __attribute__((address_space(1))) void*)(A + (size_t)row * ROWB + sir),
                (__attribute__((address_space(3))) void*)((char*)at + bo),
                16, 0, 0);
        }
    }
    __syncthreads();

    int n0 = w * 64;
    f32x4 acc[8][4] = {};
#pragma unroll
    for (int ks = 0; ks < K / 32; ks++) {
        bfx8 b[4];
#pragma unroll
        for (int nt = 0; nt < 4; nt++)
            b[nt] = *reinterpret_cast<const bfx8*>(Wt + (size_t)(n0 + nt * 16 + lr) * K + ks * 32 + lg * 8);
#pragma unroll
        for (int mt = 0; mt < 8; mt++) {
            int row = mt * 16 + lr;
            int ir = (ks * 64 + lg * 16) ^ ((lr & 7) << 4);
            bfx8 a = *reinterpret_cast<const bfx8*>((const char*)at + row * ROWB + ir);
#pragma unroll
            for (int nt = 0; nt < 4; nt++)
                acc[mt][nt] = MFMA16(a, b[nt], acc[mt][nt]);
        }
    }

#pragma unroll
    for (int nt = 0; nt < 4; nt++) {
        int col = n0 + nt * 16 + lr;
        float bv = bias[col];
#pragma unroll
        for (int mt = 0; mt < 8; mt++) {
            int rowb = m0 + mt * 16 + lg * 4;
#pragma unroll
            for (int r = 0; r < 4; r++) {
                float v = acc[mt][nt][r] + bv;
                if (RELU) v = fmaxf(v, 0.0f);
                C[(size_t)(rowb + r) * 256 + col] = f2bf(v);
            }
        }
    }
}

// ---------------- pass 1: column stats -> gs[c] = (m_c * log2e/16, 1/l_c) ----------------
// c-tile 32, grid 1024 -> 4 blocks/CU. kf[2][8] = 64 VGPR. Deferred cross-lane reduce.

__global__ __launch_bounds__(256, 4) void stats_kernel(const u16* __restrict__ q,
                                                       const u16* __restrict__ k,
                                                       float2* __restrict__ gso) {
    int flat = blockIdx.x;
    int sw = (flat & 7) * 128 + (flat >> 3);   // bijective: 1024 = 8 * 128
    int b = sw >> 6;
    int c0 = (sw & 63) * 32;
    int tid = threadIdx.x, lane = tid & 63, w = tid >> 6;
    int lr = lane & 15, lg = lane >> 4;
    const u16* qb = q + (size_t)b * NT * DIM;
    const u16* kb = k + (size_t)b * NC * DIM;
    const float A2 = 1.44269504f / 16.0f;    // log2e * scale

    bfx8 kf[2][8];
#pragma unroll
    for (int j = 0; j < 2; j++)
#pragma unroll
        for (int ks = 0; ks < 8; ks++)
            kf[j][ks] = *reinterpret_cast<const bfx8*>(kb + (size_t)(c0 + j * 16 + lr) * DIM + ks * 32 + lg * 8);

    float m_run[2], l_run[2];
#pragma unroll
    for (int j = 0; j < 2; j++) { m_run[j] = -1e30f; l_run[j] = 0.0f; }

    for (int ts = 0; ts < NT / 64; ts++) {
        int t0 = ts * 64 + w * 16;
        f32x4 acc[2] = {};
#pragma unroll
        for (int ks = 0; ks < 8; ks++) {
            bfx8 a = *reinterpret_cast<const bfx8*>(qb + (size_t)(t0 + lr) * DIM + ks * 32 + lg * 8);
#pragma unroll
            for (int j = 0; j < 2; j++)
                acc[j] = MFMA16(a, kf[j][ks], acc[j]);
        }
#pragma unroll
        for (int j = 0; j < 2; j++) {
            f32x4 a = acc[j];
            float mx = fmaxf(fmaxf(a[0], a[1]), fmaxf(a[2], a[3]));
            float mn = fmaxf(m_run[j], mx);
            float t = mn * A2;
            float sum = exp2f(fmaf(a[0], A2, -t)) + exp2f(fmaf(a[1], A2, -t)) +
                        exp2f(fmaf(a[2], A2, -t)) + exp2f(fmaf(a[3], A2, -t));
            l_run[j] = l_run[j] * exp2f(fmaf(m_run[j], A2, -t)) + sum;
            m_run[j] = mn;
        }
    }

    // intra-wave combine across the 4 lane-groups (rows), once
#pragma unroll
    for (int j = 0; j < 2; j++) {
        float m = m_run[j], l = l_run[j];
#pragma unroll
        for (int d = 16; d < 64; d <<= 1) {
            float mo = __shfl_xor(m, d);
            float lo = __shfl_xor(l, d);
            float mn = fmaxf(m, mo);
            l = l * exp2f((m - mn) * A2) + lo * exp2f((mo - mn) * A2);
            m = mn;
        }
        m_run[j] = m; l_run[j] = l;
    }

    __shared__ float sm[4][32], sl[4][32];
    if (lg == 0) {
#pragma unroll
        for (int j = 0; j < 2; j++) {
            sm[w][j * 16 + lr] = m_run[j];
            sl[w][j * 16 + lr] = l_run[j];
        }
    }
    __syncthreads();
    if (tid < 32) {
        float mf = sm[0][tid];
#pragma unroll
        for (int ww = 1; ww < 4; ww++) mf = fmaxf(mf, sm[ww][tid]);
        float lf = 0.0f;
#pragma unroll
        for (int ww = 0; ww < 4; ww++) lf += sl[ww][tid] * exp2f((sm[ww][tid] - mf) * A2);
        gso[(size_t)b * NC + c0 + tid] = make_float2(mf * A2, 1.0f / lf);
    }
}

// ---------------- pass 2: t-tile 32, grid 1024 (4 blocks/CU), 4 waves ----------
// Wave w: S quarter rows 16*(w&1), cols 16*(w>>1); PV rows 0-31, out cols 64*w.
// 2-barrier counted-vmcnt schedule (T3/T4); kt XOR-swizzled via pre-swizzled src.

__global__ __launch_bounds__(256, 4) void attn_kernel(const u16* __restrict__ q,
                                                      const u16* __restrict__ k,
                                                      const u16* __restrict__ rt,
                                                      const float2* __restrict__ gsg_,
                                                      float* __restrict__ out) {
    int flat = blockIdx.x;
    int sw = (flat & 7) * 128 + (flat >> 3);   // 2 batches per XCD
    int b = sw >> 6;
    int t0 = (sw & 63) * 32;
    int tid = threadIdx.x, lane = tid & 63, w = tid >> 6;
    int lr = lane & 15, lg = lane >> 4;
    int sr = w & 1, sc = w >> 1;              // S quarter
    const u16* qb = q + (size_t)b * NT * DIM;
    const u16* kb = k + (size_t)b * NC * DIM;
    const u16* rtb = rt + (size_t)b * DIM * NC;
    const float2* gsg = gsg_ + (size_t)b * NC;

    __shared__ __align__(16) u16 kt[2][32 * 256];   // 2 x 16 KB swizzled K tiles
    __shared__ u16 pl[32][36];                      // P tile, 72 B rows

#define STAGE(nb, cc) do {                                                          \
    const u16* ksrc_ = kb + (size_t)(cc) * DIM;                                     \
    _Pragma("unroll")                                                               \
    for (int i_ = 0; i_ < 4; i_++) {                                                \
        int off_ = ((w * 4 + i_) << 10) + (lane << 4);                              \
        int row_ = off_ >> 9;                                                       \
        int ss_  = ((off_ >> 4) & 31) ^ (row_ & 7);                                 \
        const u16* g_ = ksrc_ + row_ * DIM + ss_ * 8;                               \
        __builtin_amdgcn_global_load_lds(                                           \
            (const __attribute__((address_space(1))) void*)g_,                      \
            (__attribute__((address_space(3))) void*)(&kt[nb][(w * 4 + i_) << 9]),  \
            16, 0, 0);                                                              \
    }                                                                               \
} while (0)

    // prologue: STAGE (4 issues), then gs 1 + rb 4 + aq 8 = 13 newer -> vmcnt(13)
    STAGE(0, 0);
    __builtin_amdgcn_sched_barrier(0);
    float2 gs_c, gs_n;
    gs_c = gsg[sc * 16 + lr];
    bfx8 rb_c[4], rb_n[4];
#pragma unroll
    for (int nt = 0; nt < 4; nt++)
        rb_c[nt] = *reinterpret_cast<const bfx8*>(rtb + (size_t)(w * 64 + nt * 16 + lr) * NC + lg * 8);
    bfx8 aq[8];
#pragma unroll
    for (int ks = 0; ks < 8; ks++)
        aq[ks] = *reinterpret_cast<const bfx8*>(qb + (size_t)(t0 + sr * 16 + lr) * DIM + ks * 32 + lg * 8);
    __builtin_amdgcn_sched_barrier(0);
    asm volatile("s_waitcnt vmcnt(13)");
    __builtin_amdgcn_s_barrier();
    __builtin_amdgcn_sched_barrier(0);

    const float A = 1.44269504f / 16.0f;
    const int key = lr & 7;
    f32x4 acc[2][4] = {};
    int cur = 0;

    for (int c0 = 0; c0 < NC; c0 += 32) {
        const bool last = (c0 + 32 >= NC);
        if (!last) STAGE(cur ^ 1, c0 + 32);
        __builtin_amdgcn_sched_barrier(0);
        if (!last) {
            gs_n = gsg[c0 + 32 + sc * 16 + lr];
#pragma unroll
            for (int nt = 0; nt < 4; nt++)
                rb_n[nt] = *reinterpret_cast<const bfx8*>(rtb + (size_t)(w * 64 + nt * 16 + lr) * NC + (c0 + 32) + lg * 8);
        }

        // S quarter: 8 MFMAs from swizzled kt[cur]
        f32x4 s = {};
        {
            const char* kc = (const char*)&kt[cur][0];
#pragma unroll
            for (int ks = 0; ks < 8; ks++) {
                int slot = (ks << 2) | lg;
                bfx8 kf = *reinterpret_cast<const bfx8*>(kc + ((sc * 16 + lr) << 9) + ((slot ^ key) << 4));
                s = MFMA16(aq[ks], kf, s);
            }
        }
        // P = exp2(S*A - m') * invl -> LDS quarter
#pragma unroll
        for (int r = 0; r < 4; r++) {
            float p = exp2f(fmaf(s[r], A, -gs_c.x)) * gs_c.y;
            __bf16 h = (__bf16)p;
            pl[sr * 16 + lg * 4 + r][sc * 16 + lr] = *(u16*)&h;
        }
        __builtin_amdgcn_sched_barrier(0);
        asm volatile("s_waitcnt lgkmcnt(0)");
        __builtin_amdgcn_s_barrier();
        __builtin_amdgcn_sched_barrier(0);

        // PV: rows 0-31 (2 tiles) x wave's 4 col-tiles
#pragma unroll
        for (int mt = 0; mt < 2; mt++) {
            bfx8a pa = *reinterpret_cast<const bfx8a*>((const char*)pl + (mt * 16 + lr) * 72 + lg * 16);
#pragma unroll
            for (int nt = 0; nt < 4; nt++)
                acc[mt][nt] = MFMA16((bfx8)pa, rb_c[nt], acc[mt][nt]);
        }

        // stage drain (vmcnt(5) keeps gs_n + rb_n in flight) + P-recycle barrier
        __builtin_amdgcn_sched_barrier(0);
        asm volatile("s_waitcnt vmcnt(5) lgkmcnt(0)");
        __builtin_amdgcn_s_barrier();
        __builtin_amdgcn_sched_barrier(0);

#pragma unroll
        for (int nt = 0; nt < 4; nt++) rb_c[nt] = rb_n[nt];
        gs_c = gs_n;
        cur ^= 1;
    }
#undef STAGE

    float* ob = out + (size_t)b * NT * DIM;
#pragma unroll
    for (int mt = 0; mt < 2; mt++) {
#pragma unroll
        for (int nt = 0; nt < 4; nt++) {
            int col = w * 64 + nt * 16 + lr;
            int rowb = t0 + mt * 16 + lg * 4;
#pragma unroll
            for (int r = 0; r < 4; r++)
                ob[(size_t)(rowb + r) * DIM + col] = acc[mt][nt][r];
        }
    }
}

// ---------------- launch ----------------

extern "C" void kernel_launch(void* const* d_in, const int* in_sizes, int n_in,
                              void* d_out, int out_size, void* d_ws, size_t ws_size,
                              hipStream_t stream) {
    const float* xc  = (const float*)d_in[0];
    const float* xt  = (const float*)d_in[1];
    const float* ri  = (const float*)d_in[2];
    const float* qw1 = (const float*)d_in[3];  const float* qb1 = (const float*)d_in[4];
    const float* qw2 = (const float*)d_in[5];  const float* qb2 = (const float*)d_in[6];
    const float* qw3 = (const float*)d_in[7];  const float* qb3 = (const float*)d_in[8];
    const float* kw1 = (const float*)d_in[9];  const float* kb1 = (const float*)d_in[10];
    const float* kw2 = (const float*)d_in[11]; const float* kb2 = (const float*)d_in[12];
    const float* kw3 = (const float*)d_in[13]; const float* kb3 = (const float*)d_in[14];

    if (ws_size < ((size_t)66 << 20)) return;  // need ~65.2 MB

    char* ws = (char*)d_ws;
    u16* h1q = (u16*)(ws);
    u16* h1k = (u16*)(ws + ((size_t)16 << 20));
    u16* q   = h1q;
    u16* kk  = h1k;
    u16* h2q = (u16*)(ws + ((size_t)32 << 20));
    u16* h2k = (u16*)(ws + ((size_t)48 << 20));
    u16* rt  = h2q;
    float2* gsb = (float2*)(ws + ((size_t)64 << 20));          // 256 KB
    u16* wbuf = (u16*)(ws + ((size_t)64 << 20) + (512 << 10)); // 640 KB
    u16* qw1t = wbuf;
    u16* qw2t = qw1t + 32768;
    u16* qw3t = qw2t + 65536;
    u16* kw1t = qw3t + 65536;
    u16* kw2t = kw1t + 32768;
    u16* kw3t = kw2t + 65536;

    // weights -> transposed bf16 (one launch)
    cvt_w_all<<<dim3(1280), 256, 0, stream>>>(qw1, qw2, qw3, kw1, kw2, kw3,
                                              qw1t, qw2t, qw3t, kw1t, kw2t, kw3t);

    // fused MLP (q and k paths in one launch via blockIdx.y)
    mlp_gemm<128, true,  true ><<<dim3(256, 2), 256, 0, stream>>>(xt, xc, qw1t, kw1t, qb1, kb1, h1q, h1k);
    mlp_gemm<256, true,  false><<<dim3(256, 2), 256, 0, stream>>>(h1q, h1k, qw2t, kw2t, qb2, kb2, h2q, h2k);
    mlp_gemm<256, false, false><<<dim3(256, 2), 256, 0, stream>>>(h2q, h2k, qw3t, kw3t, qb3, kb3, q, kk);

    // r_i -> rt
    cvt_rt_kernel<<<dim3(64, 8, BB), dim3(32, 8), 0, stream>>>(ri, rt);

    // pass 1: column stats
    stats_kernel<<<dim3(1024), 256, 0, stream>>>(q, kk, gsb);

    // pass 2: attention output
    attn_kernel<<<dim3(1024), 256, 0, stream>>>(q, kk, rt, gsb, (float*)d_out);
}

// Round 7
// 358.872 us; speedup vs baseline: 1.3129x; 1.3129x over previous
//
#include <hip/hip_runtime.h>

#define BB 16
#define NT 2048
#define NC 2048
#define DIM 256
#define INDIM 128

typedef unsigned short u16;
typedef __bf16 bfx8 __attribute__((ext_vector_type(8)));
typedef __bf16 bfx8a __attribute__((ext_vector_type(8), aligned(8)));
typedef float f32x4 __attribute__((ext_vector_type(4)));

__device__ __forceinline__ u16 f2bf(float f) {
    union { float f; unsigned u; } v; v.f = f;
    return (u16)((v.u + 0x7FFFu + ((v.u >> 16) & 1u)) >> 16);
}

#define MFMA16(a, b, c) __builtin_amdgcn_mfma_f32_16x16x32_bf16((a), (b), (c), 0, 0, 0)

// ---------------- converts ----------------

// all six weight transposes in ONE launch: w[K][256] fp32 -> wt[256][K] bf16
__global__ void cvt_w_all(const float* __restrict__ w0, const float* __restrict__ w1,
                          const float* __restrict__ w2, const float* __restrict__ w3,
                          const float* __restrict__ w4, const float* __restrict__ w5,
                          u16* __restrict__ o0, u16* __restrict__ o1, u16* __restrict__ o2,
                          u16* __restrict__ o3, u16* __restrict__ o4, u16* __restrict__ o5) {
    int bx = blockIdx.x;
    const float* src; u16* dst; int K, base;
    if (bx < 128)       { src = w0; dst = o0; K = 128; base = 0; }
    else if (bx < 384)  { src = w1; dst = o1; K = 256; base = 128; }
    else if (bx < 640)  { src = w2; dst = o2; K = 256; base = 384; }
    else if (bx < 768)  { src = w3; dst = o3; K = 128; base = 640; }
    else if (bx < 1024) { src = w4; dst = o4; K = 256; base = 768; }
    else                { src = w5; dst = o5; K = 256; base = 1024; }
    int idx = (bx - base) * 256 + threadIdx.x;
    int n = idx / K, k = idx - n * K;
    dst[idx] = f2bf(src[k * 256 + n]);
}

// r [B][NC][DIM] fp32 -> rt [B][DIM][NC] bf16
__global__ void cvt_rt_kernel(const float* __restrict__ r, u16* __restrict__ rt) {
    __shared__ u16 tile[32][33];
    int b = blockIdx.z;
    int c0 = blockIdx.x * 32, d0 = blockIdx.y * 32;
    int tx = threadIdx.x, ty = threadIdx.y; // (32, 8)
    const float* rb = r + (size_t)b * NC * DIM;
#pragma unroll
    for (int i = 0; i < 4; i++) {
        int c = c0 + ty + i * 8;
        tile[ty + i * 8][tx] = f2bf(rb[(size_t)c * DIM + d0 + tx]);
    }
    __syncthreads();
    u16* rtb = rt + (size_t)b * DIM * NC;
#pragma unroll
    for (int i = 0; i < 4; i++) {
        int d = d0 + ty + i * 8;
        rtb[(size_t)d * NC + c0 + tx] = tile[tx][ty + i * 8];
    }
}

// ---------------- fused MLP layer: C[M,256] = act(A[M,K] @ Wt[256,K]^T + b) --------------

template <int K, bool RELU, bool CVTIN>
__global__ __launch_bounds__(256) void mlp_gemm(const void* __restrict__ Aq, const void* __restrict__ Ak,
                                                const u16* __restrict__ Wq, const u16* __restrict__ Wk,
                                                const float* __restrict__ bq, const float* __restrict__ bk,
                                                u16* __restrict__ Cq, u16* __restrict__ Ck) {
    constexpr int ROWB = K * 2;          // A-tile row bytes (bf16)
    constexpr int NCH = K / 16;          // 16B chunks per thread
    __shared__ __align__(16) u16 at[128 * K];

    int tid = threadIdx.x, lane = tid & 63, w = tid >> 6;
    int lr = lane & 15, lg = lane >> 4;
    int m0 = blockIdx.x * 128;
    bool isq = (blockIdx.y == 0);
    const u16* Wt = isq ? Wq : Wk;
    const float* bias = isq ? bq : bk;
    u16* C = isq ? Cq : Ck;

    if (CVTIN) {
        const float* A = (const float*)(isq ? Aq : Ak) + (size_t)m0 * K;
#pragma unroll
        for (int j = 0; j < NCH; j++) {
            int bo = tid * (NCH * 16) + j * 16;
            int row = bo >> 8;                        // K=128: 256 B rows
            int ir = bo & (ROWB - 1);
            const float* src = A + (size_t)row * K + (ir >> 1);
            float4 f0 = *reinterpret_cast<const float4*>(src);
            float4 f1 = *reinterpret_cast<const float4*>(src + 4);
            union { u16 u[8]; uint4 v; } pk;
            {
                __bf16 h;
                h = (__bf16)f0.x; pk.u[0] = *(u16*)&h;
                h = (__bf16)f0.y; pk.u[1] = *(u16*)&h;
                h = (__bf16)f0.z; pk.u[2] = *(u16*)&h;
                h = (__bf16)f0.w; pk.u[3] = *(u16*)&h;
                h = (__bf16)f1.x; pk.u[4] = *(u16*)&h;
                h = (__bf16)f1.y; pk.u[5] = *(u16*)&h;
                h = (__bf16)f1.z; pk.u[6] = *(u16*)&h;
                h = (__bf16)f1.w; pk.u[7] = *(u16*)&h;
            }
            int dst = row * ROWB + (ir ^ ((row & 7) << 4));
            *reinterpret_cast<uint4*>((char*)at + dst) = pk.v;
        }
    } else {
        const char* A = (const char*)((const u16*)(isq ? Aq : Ak) + (size_t)m0 * K);
#pragma unroll
        for (int j = 0; j < NCH; j++) {
            int bo = j * 4096 + tid * 16;
            int row = bo >> 9;                        // K=256: 512 B rows
            int ir = bo & (ROWB - 1);
            int sir = ir ^ ((row & 7) << 4);
            __builtin_amdgcn_global_load_lds(
                (const __attribute__((address_space(1))) void*)(A + (size_t)row * ROWB + sir),
                (__attribute__((address_space(3))) void*)((char*)at + bo),
                16, 0, 0);
        }
    }
    __syncthreads();

    int n0 = w * 64;
    f32x4 acc[8][4] = {};
#pragma unroll
    for (int ks = 0; ks < K / 32; ks++) {
        bfx8 b[4];
#pragma unroll
        for (int nt = 0; nt < 4; nt++)
            b[nt] = *reinterpret_cast<const bfx8*>(Wt + (size_t)(n0 + nt * 16 + lr) * K + ks * 32 + lg * 8);
#pragma unroll
        for (int mt = 0; mt < 8; mt++) {
            int row = mt * 16 + lr;
            int ir = (ks * 64 + lg * 16) ^ ((lr & 7) << 4);
            bfx8 a = *reinterpret_cast<const bfx8*>((const char*)at + row * ROWB + ir);
#pragma unroll
            for (int nt = 0; nt < 4; nt++)
                acc[mt][nt] = MFMA16(a, b[nt], acc[mt][nt]);
        }
    }

#pragma unroll
    for (int nt = 0; nt < 4; nt++) {
        int col = n0 + nt * 16 + lr;
        float bv = bias[col];
#pragma unroll
        for (int mt = 0; mt < 8; mt++) {
            int rowb = m0 + mt * 16 + lg * 4;
#pragma unroll
            for (int r = 0; r < 4; r++) {
                float v = acc[mt][nt][r] + bv;
                if (RELU) v = fmaxf(v, 0.0f);
                C[(size_t)(rowb + r) * 256 + col] = f2bf(v);
            }
        }
    }
}

// ---------------- pass 1: column stats -> gs[c] = (m_c * log2e/16, 1/l_c) ----------------
// c-tile 64, grid 512 (round-5 proven). Deferred cross-lane reduce, exp2 domain.

__global__ __launch_bounds__(256) void stats_kernel(const u16* __restrict__ q,
                                                    const u16* __restrict__ k,
                                                    float2* __restrict__ gso) {
    int flat = blockIdx.x;
    int sw = (flat & 7) * 64 + (flat >> 3);   // bijective XCD swizzle: 2 batches/XCD
    int b = sw >> 5;
    int c0 = (sw & 31) * 64;
    int tid = threadIdx.x, lane = tid & 63, w = tid >> 6;
    int lr = lane & 15, lg = lane >> 4;
    const u16* qb = q + (size_t)b * NT * DIM;
    const u16* kb = k + (size_t)b * NC * DIM;
    const float A2 = 1.44269504f / 16.0f;    // log2e * scale

    bfx8 kf[4][8];
#pragma unroll
    for (int j = 0; j < 4; j++)
#pragma unroll
        for (int ks = 0; ks < 8; ks++)
            kf[j][ks] = *reinterpret_cast<const bfx8*>(kb + (size_t)(c0 + j * 16 + lr) * DIM + ks * 32 + lg * 8);

    float m_run[4], l_run[4];
#pragma unroll
    for (int j = 0; j < 4; j++) { m_run[j] = -1e30f; l_run[j] = 0.0f; }

    for (int ts = 0; ts < NT / 64; ts++) {
        int t0 = ts * 64 + w * 16;
        f32x4 acc[4] = {};
#pragma unroll
        for (int ks = 0; ks < 8; ks++) {
            bfx8 a = *reinterpret_cast<const bfx8*>(qb + (size_t)(t0 + lr) * DIM + ks * 32 + lg * 8);
#pragma unroll
            for (int j = 0; j < 4; j++)
                acc[j] = MFMA16(a, kf[j][ks], acc[j]);
        }
#pragma unroll
        for (int j = 0; j < 4; j++) {
            f32x4 a = acc[j];
            float mx = fmaxf(fmaxf(a[0], a[1]), fmaxf(a[2], a[3]));
            float mn = fmaxf(m_run[j], mx);
            float t = mn * A2;
            float sum = exp2f(fmaf(a[0], A2, -t)) + exp2f(fmaf(a[1], A2, -t)) +
                        exp2f(fmaf(a[2], A2, -t)) + exp2f(fmaf(a[3], A2, -t));
            l_run[j] = l_run[j] * exp2f(fmaf(m_run[j], A2, -t)) + sum;
            m_run[j] = mn;
        }
    }

    // intra-wave combine across the 4 lane-groups (rows), once
#pragma unroll
    for (int j = 0; j < 4; j++) {
        float m = m_run[j], l = l_run[j];
#pragma unroll
        for (int d = 16; d < 64; d <<= 1) {
            float mo = __shfl_xor(m, d);
            float lo = __shfl_xor(l, d);
            float mn = fmaxf(m, mo);
            l = l * exp2f((m - mn) * A2) + lo * exp2f((mo - mn) * A2);
            m = mn;
        }
        m_run[j] = m; l_run[j] = l;
    }

    __shared__ float sm[4][64], sl[4][64];
    if (lg == 0) {
#pragma unroll
        for (int j = 0; j < 4; j++) {
            sm[w][j * 16 + lr] = m_run[j];
            sl[w][j * 16 + lr] = l_run[j];
        }
    }
    __syncthreads();
    if (tid < 64) {
        float mf = sm[0][tid];
#pragma unroll
        for (int ww = 1; ww < 4; ww++) mf = fmaxf(mf, sm[ww][tid]);
        float lf = 0.0f;
#pragma unroll
        for (int ww = 0; ww < 4; ww++) lf += sl[ww][tid] * exp2f((sm[ww][tid] - mf) * A2);
        gso[(size_t)b * NC + c0 + tid] = make_float2(mf * A2, 1.0f / lf);
    }
}

// ---------------- pass 2: t=64, c-step 64, 4 waves, 2 barriers per 64-MFMA iter ----------
// Wave w: S rows [16w,16w+16) x 64 cols (32 MFMA); PV rows 0-63 x out cols [64w,64w+64)
// (32 MFMA). kt dbuf 2x32KB XOR-swizzled (pre-swizzled global src). rb/gs loaded per-iter
// BEFORE the STAGE issue so staging ops are newest in the vmcnt FIFO; top-of-iter
// vmcnt(20) (last: 12) drains only the previous tile's 8 staging loads.

__global__ __launch_bounds__(256) void attn_kernel(const u16* __restrict__ q,
                                                   const u16* __restrict__ k,
                                                   const u16* __restrict__ rt,
                                                   const float2* __restrict__ gsg_,
                                                   float* __restrict__ out) {
    int flat = blockIdx.x;
    int sw = (flat & 7) * 64 + (flat >> 3);   // 2 batches per XCD
    int b = sw >> 5;
    int t0 = (sw & 31) * 64;
    int tid = threadIdx.x, lane = tid & 63, w = tid >> 6;
    int lr = lane & 15, lg = lane >> 4;
    const u16* qb = q + (size_t)b * NT * DIM;
    const u16* kb = k + (size_t)b * NC * DIM;
    const u16* rtb = rt + (size_t)b * DIM * NC;
    const float2* gsg = gsg_ + (size_t)b * NC;

    __shared__ __align__(16) u16 kt[2][64 * 256];   // 2 x 32 KB swizzled K tiles
    __shared__ __align__(16) u16 pl[64][72];        // P tile, 144 B rows (bank stride 4)

#define STAGE(nb, cc) do {                                                          \
    const u16* ksrc_ = kb + (size_t)(cc) * DIM;                                     \
    _Pragma("unroll")                                                               \
    for (int i_ = 0; i_ < 8; i_++) {                                                \
        int off_ = ((w * 8 + i_) << 10) + (lane << 4);                              \
        int row_ = off_ >> 9;                                                       \
        int ss_  = ((off_ >> 4) & 31) ^ (row_ & 7);                                 \
        const u16* g_ = ksrc_ + row_ * DIM + ss_ * 8;                               \
        __builtin_amdgcn_global_load_lds(                                           \
            (const __attribute__((address_space(1))) void*)g_,                      \
            (__attribute__((address_space(3))) void*)(&kt[nb][(w * 8 + i_) << 9]),  \
            16, 0, 0);                                                              \
    }                                                                               \
} while (0)

    // hoist q fragments (wave's 16 S-rows, full K=256)
    bfx8 aq[8];
#pragma unroll
    for (int ks = 0; ks < 8; ks++)
        aq[ks] = *reinterpret_cast<const bfx8*>(qb + (size_t)(t0 + w * 16 + lr) * DIM + ks * 32 + lg * 8);

    // prologue: stage tile 0 (8 issues, oldest in FIFO at iter 0)
    __builtin_amdgcn_sched_barrier(0);
    STAGE(0, 0);
    __builtin_amdgcn_sched_barrier(0);

    const float A = 1.44269504f / 16.0f;   // log2e * (1/sqrt(256))
    const int key = lr & 7;
    f32x4 acc[4][4] = {};
    int cur = 0;

    for (int it = 0; it < NC / 64; ++it) {
        const int c0 = it * 64;
        const bool last = (it == NC / 64 - 1);

        // region 1: this-iter consumable loads (g, rb) — OLDER than the new stage
        float2 g[4];
#pragma unroll
        for (int j = 0; j < 4; j++) g[j] = gsg[c0 + j * 16 + lr];
        bfx8 rb[8];
#pragma unroll
        for (int nt = 0; nt < 4; nt++)
#pragma unroll
            for (int kk = 0; kk < 2; kk++)
                rb[nt * 2 + kk] = *reinterpret_cast<const bfx8*>(
                    rtb + (size_t)(w * 64 + nt * 16 + lr) * NC + c0 + kk * 32 + lg * 8);
        __builtin_amdgcn_sched_barrier(0);
        // region 2: next-tile staging (newest in FIFO)
        if (!last) STAGE(cur ^ 1, c0 + 64);
        __builtin_amdgcn_sched_barrier(0);
        // top barrier: previous tile's 8 staging loads done (20 = g4+rb8+stage8 newer)
        if (!last) asm volatile("s_waitcnt vmcnt(20)");
        else       asm volatile("s_waitcnt vmcnt(12)");
        __builtin_amdgcn_s_barrier();
        __builtin_amdgcn_sched_barrier(0);

        // S phase: 32 MFMAs, wave's 16 rows x 64 cols from swizzled kt[cur]
        f32x4 s[4] = {};
        {
            const char* kc = (const char*)&kt[cur][0];
#pragma unroll
            for (int ks = 0; ks < 8; ks++) {
                int slot = (ks << 2) | lg;
#pragma unroll
                for (int j = 0; j < 4; j++) {
                    bfx8 kf = *reinterpret_cast<const bfx8*>(kc + ((j * 16 + lr) << 9) + ((slot ^ key) << 4));
                    s[j] = MFMA16(aq[ks], kf, s[j]);
                }
            }
        }
        // P = exp2(S*A - m') * invl -> LDS (compiler's own vmcnt covers g; stage survives)
#pragma unroll
        for (int j = 0; j < 4; j++) {
#pragma unroll
            for (int r = 0; r < 4; r++) {
                float p = exp2f(fmaf(s[j][r], A, -g[j].x)) * g[j].y;
                __bf16 h = (__bf16)p;
                pl[w * 16 + lg * 4 + r][j * 16 + lr] = *(u16*)&h;
            }
        }
        // mid barrier: P hand-off (lgkm only; staging stays in flight)
        __builtin_amdgcn_sched_barrier(0);
        asm volatile("s_waitcnt lgkmcnt(0)");
        __builtin_amdgcn_s_barrier();
        __builtin_amdgcn_sched_barrier(0);

        // PV phase: 32 MFMAs (4 row-tiles x 4 col-tiles x K=64)
#pragma unroll
        for (int kk = 0; kk < 2; kk++) {
#pragma unroll
            for (int mt = 0; mt < 4; mt++) {
                bfx8a pa = *reinterpret_cast<const bfx8a*>(
                    (const char*)pl + (mt * 16 + lr) * 144 + kk * 64 + lg * 16);
#pragma unroll
                for (int nt = 0; nt < 4; nt++)
                    acc[mt][nt] = MFMA16((bfx8)pa, rb[nt * 2 + kk], acc[mt][nt]);
            }
        }
        cur ^= 1;
    }
#undef STAGE

    float* ob = out + (size_t)b * NT * DIM;
#pragma unroll
    for (int nt = 0; nt < 4; nt++) {
        int col = w * 64 + nt * 16 + lr;
#pragma unroll
        for (int mt = 0; mt < 4; mt++) {
            int rowb = t0 + mt * 16 + lg * 4;
#pragma unroll
            for (int r = 0; r < 4; r++)
                ob[(size_t)(rowb + r) * DIM + col] = acc[mt][nt][r];
        }
    }
}

// ---------------- launch ----------------

extern "C" void kernel_launch(void* const* d_in, const int* in_sizes, int n_in,
                              void* d_out, int out_size, void* d_ws, size_t ws_size,
                              hipStream_t stream) {
    const float* xc  = (const float*)d_in[0];
    const float* xt  = (const float*)d_in[1];
    const float* ri  = (const float*)d_in[2];
    const float* qw1 = (const float*)d_in[3];  const float* qb1 = (const float*)d_in[4];
    const float* qw2 = (const float*)d_in[5];  const float* qb2 = (const float*)d_in[6];
    const float* qw3 = (const float*)d_in[7];  const float* qb3 = (const float*)d_in[8];
    const float* kw1 = (const float*)d_in[9];  const float* kb1 = (const float*)d_in[10];
    const float* kw2 = (const float*)d_in[11]; const float* kb2 = (const float*)d_in[12];
    const float* kw3 = (const float*)d_in[13]; const float* kb3 = (const float*)d_in[14];

    if (ws_size < ((size_t)66 << 20)) return;  // need ~65.2 MB

    char* ws = (char*)d_ws;
    u16* h1q = (u16*)(ws);
    u16* h1k = (u16*)(ws + ((size_t)16 << 20));
    u16* q   = h1q;
    u16* kk  = h1k;
    u16* h2q = (u16*)(ws + ((size_t)32 << 20));
    u16* h2k = (u16*)(ws + ((size_t)48 << 20));
    u16* rt  = h2q;
    float2* gsb = (float2*)(ws + ((size_t)64 << 20));          // 256 KB
    u16* wbuf = (u16*)(ws + ((size_t)64 << 20) + (512 << 10)); // 640 KB
    u16* qw1t = wbuf;
    u16* qw2t = qw1t + 32768;
    u16* qw3t = qw2t + 65536;
    u16* kw1t = qw3t + 65536;
    u16* kw2t = kw1t + 32768;
    u16* kw3t = kw2t + 65536;

    // weights -> transposed bf16 (one launch)
    cvt_w_all<<<dim3(1280), 256, 0, stream>>>(qw1, qw2, qw3, kw1, kw2, kw3,
                                              qw1t, qw2t, qw3t, kw1t, kw2t, kw3t);

    // fused MLP (q and k paths in one launch via blockIdx.y)
    mlp_gemm<128, true,  true ><<<dim3(256, 2), 256, 0, stream>>>(xt, xc, qw1t, kw1t, qb1, kb1, h1q, h1k);
    mlp_gemm<256, true,  false><<<dim3(256, 2), 256, 0, stream>>>(h1q, h1k, qw2t, kw2t, qb2, kb2, h2q, h2k);
    mlp_gemm<256, false, false><<<dim3(256, 2), 256, 0, stream>>>(h2q, h2k, qw3t, kw3t, qb3, kb3, q, kk);

    // r_i -> rt
    cvt_rt_kernel<<<dim3(64, 8, BB), dim3(32, 8), 0, stream>>>(ri, rt);

    // pass 1: column stats
    stats_kernel<<<dim3(512), 256, 0, stream>>>(q, kk, gsb);

    // pass 2: attention output
    attn_kernel<<<dim3(512), 256, 0, stream>>>(q, kk, rt, gsb, (float*)d_out);
}

// Round 8
// 334.929 us; speedup vs baseline: 1.4067x; 1.0715x over previous
//
#include <hip/hip_runtime.h>

#define BB 16
#define NT 2048
#define NC 2048
#define DIM 256
#define INDIM 128

typedef unsigned short u16;
typedef __bf16 bfx8 __attribute__((ext_vector_type(8)));
typedef float f32x4 __attribute__((ext_vector_type(4)));

__device__ __forceinline__ u16 f2bf(float f) {
    union { float f; unsigned u; } v; v.f = f;
    return (u16)((v.u + 0x7FFFu + ((v.u >> 16) & 1u)) >> 16);
}

#define MFMA16(a, b, c) __builtin_amdgcn_mfma_f32_16x16x32_bf16((a), (b), (c), 0, 0, 0)

// ---------------- converts ----------------

// all six weight transposes in ONE launch: w[K][256] fp32 -> wt[256][K] bf16
__global__ void cvt_w_all(const float* __restrict__ w0, const float* __restrict__ w1,
                          const float* __restrict__ w2, const float* __restrict__ w3,
                          const float* __restrict__ w4, const float* __restrict__ w5,
                          u16* __restrict__ o0, u16* __restrict__ o1, u16* __restrict__ o2,
                          u16* __restrict__ o3, u16* __restrict__ o4, u16* __restrict__ o5) {
    int bx = blockIdx.x;
    const float* src; u16* dst; int K, base;
    if (bx < 128)       { src = w0; dst = o0; K = 128; base = 0; }
    else if (bx < 384)  { src = w1; dst = o1; K = 256; base = 128; }
    else if (bx < 640)  { src = w2; dst = o2; K = 256; base = 384; }
    else if (bx < 768)  { src = w3; dst = o3; K = 128; base = 640; }
    else if (bx < 1024) { src = w4; dst = o4; K = 256; base = 768; }
    else                { src = w5; dst = o5; K = 256; base = 1024; }
    int idx = (bx - base) * 256 + threadIdx.x;
    int n = idx / K, k = idx - n * K;
    dst[idx] = f2bf(src[k * 256 + n]);
}

// r [B][NC][DIM] fp32 -> rt [B][DIM][NC] bf16
__global__ void cvt_rt_kernel(const float* __restrict__ r, u16* __restrict__ rt) {
    __shared__ u16 tile[32][33];
    int b = blockIdx.z;
    int c0 = blockIdx.x * 32, d0 = blockIdx.y * 32;
    int tx = threadIdx.x, ty = threadIdx.y; // (32, 8)
    const float* rb = r + (size_t)b * NC * DIM;
#pragma unroll
    for (int i = 0; i < 4; i++) {
        int c = c0 + ty + i * 8;
        tile[ty + i * 8][tx] = f2bf(rb[(size_t)c * DIM + d0 + tx]);
    }
    __syncthreads();
    u16* rtb = rt + (size_t)b * DIM * NC;
#pragma unroll
    for (int i = 0; i < 4; i++) {
        int d = d0 + ty + i * 8;
        rtb[(size_t)d * NC + c0 + tx] = tile[tx][ty + i * 8];
    }
}

// ---------------- fused MLP layer: C[M,256] = act(A[M,K] @ Wt[256,K]^T + b) --------------

template <int K, bool RELU, bool CVTIN>
__global__ __launch_bounds__(256) void mlp_gemm(const void* __restrict__ Aq, const void* __restrict__ Ak,
                                                const u16* __restrict__ Wq, const u16* __restrict__ Wk,
                                                const float* __restrict__ bq, const float* __restrict__ bk,
                                                u16* __restrict__ Cq, u16* __restrict__ Ck) {
    constexpr int ROWB = K * 2;          // A-tile row bytes (bf16)
    constexpr int NCH = K / 16;          // 16B chunks per thread
    __shared__ __align__(16) u16 at[128 * K];

    int tid = threadIdx.x, lane = tid & 63, w = tid >> 6;
    int lr = lane & 15, lg = lane >> 4;
    int m0 = blockIdx.x * 128;
    bool isq = (blockIdx.y == 0);
    const u16* Wt = isq ? Wq : Wk;
    const float* bias = isq ? bq : bk;
    u16* C = isq ? Cq : Ck;

    if (CVTIN) {
        const float* A = (const float*)(isq ? Aq : Ak) + (size_t)m0 * K;
#pragma unroll
        for (int j = 0; j < NCH; j++) {
            int bo = tid * (NCH * 16) + j * 16;
            int row = bo >> 8;                        // K=128: 256 B rows
            int ir = bo & (ROWB - 1);
            const float* src = A + (size_t)row * K + (ir >> 1);
            float4 f0 = *reinterpret_cast<const float4*>(src);
            float4 f1 = *reinterpret_cast<const float4*>(src + 4);
            union { u16 u[8]; uint4 v; } pk;
            {
                __bf16 h;
                h = (__bf16)f0.x; pk.u[0] = *(u16*)&h;
                h = (__bf16)f0.y; pk.u[1] = *(u16*)&h;
                h = (__bf16)f0.z; pk.u[2] = *(u16*)&h;
                h = (__bf16)f0.w; pk.u[3] = *(u16*)&h;
                h = (__bf16)f1.x; pk.u[4] = *(u16*)&h;
                h = (__bf16)f1.y; pk.u[5] = *(u16*)&h;
                h = (__bf16)f1.z; pk.u[6] = *(u16*)&h;
                h = (__bf16)f1.w; pk.u[7] = *(u16*)&h;
            }
            int dst = row * ROWB + (ir ^ ((row & 7) << 4));
            *reinterpret_cast<uint4*>((char*)at + dst) = pk.v;
        }
    } else {
        const char* A = (const char*)((const u16*)(isq ? Aq : Ak) + (size_t)m0 * K);
#pragma unroll
        for (int j = 0; j < NCH; j++) {
            int bo = j * 4096 + tid * 16;
            int row = bo >> 9;                        // K=256: 512 B rows
            int ir = bo & (ROWB - 1);
            int sir = ir ^ ((row & 7) << 4);
            __builtin_amdgcn_global_load_lds(
                (const __attribute__((address_space(1))) void*)(A + (size_t)row * ROWB + sir),
                (__attribute__((address_space(3))) void*)((char*)at + bo),
                16, 0, 0);
        }
    }
    __syncthreads();

    int n0 = w * 64;
    f32x4 acc[8][4] = {};
#pragma unroll
    for (int ks = 0; ks < K / 32; ks++) {
        bfx8 b[4];
#pragma unroll
        for (int nt = 0; nt < 4; nt++)
            b[nt] = *reinterpret_cast<const bfx8*>(Wt + (size_t)(n0 + nt * 16 + lr) * K + ks * 32 + lg * 8);
#pragma unroll
        for (int mt = 0; mt < 8; mt++) {
            int row = mt * 16 + lr;
            int ir = (ks * 64 + lg * 16) ^ ((lr & 7) << 4);
            bfx8 a = *reinterpret_cast<const bfx8*>((const char*)at + row * ROWB + ir);
#pragma unroll
            for (int nt = 0; nt < 4; nt++)
                acc[mt][nt] = MFMA16(a, b[nt], acc[mt][nt]);
        }
    }

#pragma unroll
    for (int nt = 0; nt < 4; nt++) {
        int col = n0 + nt * 16 + lr;
        float bv = bias[col];
#pragma unroll
        for (int mt = 0; mt < 8; mt++) {
            int rowb = m0 + mt * 16 + lg * 4;
#pragma unroll
            for (int r = 0; r < 4; r++) {
                float v = acc[mt][nt][r] + bv;
                if (RELU) v = fmaxf(v, 0.0f);
                C[(size_t)(rowb + r) * 256 + col] = f2bf(v);
            }
        }
    }
}

// ---------------- pass 1: column stats -> gs[c] = (m_c * log2e/16, 1/l_c) ----------------

__global__ __launch_bounds__(256) void stats_kernel(const u16* __restrict__ q,
                                                    const u16* __restrict__ k,
                                                    float2* __restrict__ gso) {
    int flat = blockIdx.x;
    int sw = (flat & 7) * 64 + (flat >> 3);   // bijective XCD swizzle: 2 batches/XCD
    int b = sw >> 5;
    int c0 = (sw & 31) * 64;
    int tid = threadIdx.x, lane = tid & 63, w = tid >> 6;
    int lr = lane & 15, lg = lane >> 4;
    const u16* qb = q + (size_t)b * NT * DIM;
    const u16* kb = k + (size_t)b * NC * DIM;
    const float A2 = 1.44269504f / 16.0f;    // log2e * scale

    bfx8 kf[4][8];
#pragma unroll
    for (int j = 0; j < 4; j++)
#pragma unroll
        for (int ks = 0; ks < 8; ks++)
            kf[j][ks] = *reinterpret_cast<const bfx8*>(kb + (size_t)(c0 + j * 16 + lr) * DIM + ks * 32 + lg * 8);

    float m_run[4], l_run[4];
#pragma unroll
    for (int j = 0; j < 4; j++) { m_run[j] = -1e30f; l_run[j] = 0.0f; }

    for (int ts = 0; ts < NT / 64; ts++) {
        int t0 = ts * 64 + w * 16;
        f32x4 acc[4] = {};
#pragma unroll
        for (int ks = 0; ks < 8; ks++) {
            bfx8 a = *reinterpret_cast<const bfx8*>(qb + (size_t)(t0 + lr) * DIM + ks * 32 + lg * 8);
#pragma unroll
            for (int j = 0; j < 4; j++)
                acc[j] = MFMA16(a, kf[j][ks], acc[j]);
        }
#pragma unroll
        for (int j = 0; j < 4; j++) {
            f32x4 a = acc[j];
            float mx = fmaxf(fmaxf(a[0], a[1]), fmaxf(a[2], a[3]));
            float mn = fmaxf(m_run[j], mx);
            float t = mn * A2;
            float sum = exp2f(fmaf(a[0], A2, -t)) + exp2f(fmaf(a[1], A2, -t)) +
                        exp2f(fmaf(a[2], A2, -t)) + exp2f(fmaf(a[3], A2, -t));
            l_run[j] = l_run[j] * exp2f(fmaf(m_run[j], A2, -t)) + sum;
            m_run[j] = mn;
        }
    }

    // intra-wave combine across the 4 lane-groups (rows), once
#pragma unroll
    for (int j = 0; j < 4; j++) {
        float m = m_run[j], l = l_run[j];
#pragma unroll
        for (int d = 16; d < 64; d <<= 1) {
            float mo = __shfl_xor(m, d);
            float lo = __shfl_xor(l, d);
            float mn = fmaxf(m, mo);
            l = l * exp2f((m - mn) * A2) + lo * exp2f((mo - mn) * A2);
            m = mn;
        }
        m_run[j] = m; l_run[j] = l;
    }

    __shared__ float sm[4][64], sl[4][64];
    if (lg == 0) {
#pragma unroll
        for (int j = 0; j < 4; j++) {
            sm[w][j * 16 + lr] = m_run[j];
            sl[w][j * 16 + lr] = l_run[j];
        }
    }
    __syncthreads();
    if (tid < 64) {
        float mf = sm[0][tid];
#pragma unroll
        for (int ww = 1; ww < 4; ww++) mf = fmaxf(mf, sm[ww][tid]);
        float lf = 0.0f;
#pragma unroll
        for (int ww = 0; ww < 4; ww++) lf += sl[ww][tid] * exp2f((sm[ww][tid] - mf) * A2);
        gso[(size_t)b * NC + c0 + tid] = make_float2(mf * A2, 1.0f / lf);
    }
}

// ---------------- pass 2: c-step 64, SINGLE 32KB kt buffer, 2 barriers/iter ----------
// LDS 41 KB -> 2 blocks/CU. Per iter: S(32 MFMA) -> exp -> P write -> lgkm0+barrier1
// (kt reads done + P ready) -> STAGE next tile (oldest in FIFO) + rb_n/g_n (newer) ->
// PV(32 MFMA, rb_c) -> vmcnt(12)+barrier2 (drain OWN stage -> global after barrier;
// rb_n/g_n stay in flight). Stage latency hides under PV; waves skew within regions.

__global__ __launch_bounds__(256) void attn_kernel(const u16* __restrict__ q,
                                                   const u16* __restrict__ k,
                                                   const u16* __restrict__ rt,
                                                   const float2* __restrict__ gsg_,
                                                   float* __restrict__ out) {
    int flat = blockIdx.x;
    int sw = (flat & 7) * 64 + (flat >> 3);   // 2 batches per XCD
    int b = sw >> 5;
    int t0 = (sw & 31) * 64;
    int tid = threadIdx.x, lane = tid & 63, w = tid >> 6;
    int lr = lane & 15, lg = lane >> 4;
    const u16* qb = q + (size_t)b * NT * DIM;
    const u16* kb = k + (size_t)b * NC * DIM;
    const u16* rtb = rt + (size_t)b * DIM * NC;
    const float2* gsg = gsg_ + (size_t)b * NC;

    __shared__ __align__(16) u16 kt[64 * 256];      // 32 KB swizzled K tile (single)
    __shared__ __align__(16) u16 pl[64][72];        // shared P tile, 144 B rows

#define STAGE(cc) do {                                                          \
    const u16* ksrc_ = kb + (size_t)(cc) * DIM;                                 \
    _Pragma("unroll")                                                           \
    for (int i_ = 0; i_ < 8; i_++) {                                            \
        int off_ = ((w * 8 + i_) << 10) + (lane << 4);                          \
        int row_ = off_ >> 9;                                                   \
        int ss_  = ((off_ >> 4) & 31) ^ (row_ & 7);                             \
        const u16* g_ = ksrc_ + row_ * DIM + ss_ * 8;                           \
        __builtin_amdgcn_global_load_lds(                                       \
            (const __attribute__((address_space(1))) void*)g_,                  \
            (__attribute__((address_space(3))) void*)(&kt[(w * 8 + i_) << 9]),  \
            16, 0, 0);                                                          \
    }                                                                           \
} while (0)

    // hoist q fragments (wave's 16 S-rows, full K=256)
    bfx8 aq[8];
#pragma unroll
    for (int ks = 0; ks < 8; ks++)
        aq[ks] = *reinterpret_cast<const bfx8*>(qb + (size_t)(t0 + w * 16 + lr) * DIM + ks * 32 + lg * 8);

    // prologue: STAGE tile0 (8, oldest), then rb_c (8) + g_c (4) newer -> vmcnt(12)
    __builtin_amdgcn_sched_barrier(0);
    STAGE(0);
    __builtin_amdgcn_sched_barrier(0);
    bfx8 rb_c[8], rb_n[8];
#pragma unroll
    for (int nt = 0; nt < 4; nt++)
#pragma unroll
        for (int kk = 0; kk < 2; kk++)
            rb_c[nt * 2 + kk] = *reinterpret_cast<const bfx8*>(
                rtb + (size_t)(w * 64 + nt * 16 + lr) * NC + kk * 32 + lg * 8);
    float2 g_c[4], g_n[4];
#pragma unroll
    for (int j = 0; j < 4; j++) g_c[j] = gsg[j * 16 + lr];
    __builtin_amdgcn_sched_barrier(0);
    asm volatile("s_waitcnt vmcnt(12)");
    __builtin_amdgcn_s_barrier();
    __builtin_amdgcn_sched_barrier(0);

    const float A = 1.44269504f / 16.0f;   // log2e * (1/sqrt(256))
    const int key = lr & 7;
    f32x4 acc[4][4] = {};

    for (int it = 0; it < NC / 64; ++it) {
        const int c0 = it * 64;
        const bool last = (it == NC / 64 - 1);

        // S phase: 32 MFMAs, wave's 16 rows x 64 cols from swizzled kt
        f32x4 s[4] = {};
        {
            const char* kc = (const char*)&kt[0];
#pragma unroll
            for (int ks = 0; ks < 8; ks++) {
                int slot = (ks << 2) | lg;
#pragma unroll
                for (int j = 0; j < 4; j++) {
                    bfx8 kf = *reinterpret_cast<const bfx8*>(kc + ((j * 16 + lr) << 9) + ((slot ^ key) << 4));
                    s[j] = MFMA16(aq[ks], kf, s[j]);
                }
            }
        }
        // P = exp2(S*A - m') * invl -> shared pl (this wave's 16 rows)
#pragma unroll
        for (int j = 0; j < 4; j++) {
#pragma unroll
            for (int r = 0; r < 4; r++) {
                float p = exp2f(fmaf(s[j][r], A, -g_c[j].x)) * g_c[j].y;
                __bf16 h = (__bf16)p;
                pl[w * 16 + lg * 4 + r][j * 16 + lr] = *(u16*)&h;
            }
        }
        // barrier1: all waves done reading kt AND P visible
        __builtin_amdgcn_sched_barrier(0);
        asm volatile("s_waitcnt lgkmcnt(0)");
        __builtin_amdgcn_s_barrier();
        __builtin_amdgcn_sched_barrier(0);

        // stage next tile (oldest), then next-iter rb/g (newer)
        if (!last) {
            STAGE(c0 + 64);
            __builtin_amdgcn_sched_barrier(0);
#pragma unroll
            for (int j = 0; j < 4; j++) g_n[j] = gsg[c0 + 64 + j * 16 + lr];
#pragma unroll
            for (int nt = 0; nt < 4; nt++)
#pragma unroll
                for (int kk = 0; kk < 2; kk++)
                    rb_n[nt * 2 + kk] = *reinterpret_cast<const bfx8*>(
                        rtb + (size_t)(w * 64 + nt * 16 + lr) * NC + (c0 + 64) + kk * 32 + lg * 8);
        }
        __builtin_amdgcn_sched_barrier(0);

        // PV phase: 32 MFMAs (4 row-tiles x 4 col-tiles x K=64), reads shared pl
#pragma unroll
        for (int kk = 0; kk < 2; kk++) {
#pragma unroll
            for (int mt = 0; mt < 4; mt++) {
                bfx8 pa = *reinterpret_cast<const bfx8*>(
                    (const char*)pl + (mt * 16 + lr) * 144 + kk * 64 + lg * 16);
#pragma unroll
                for (int nt = 0; nt < 4; nt++)
                    acc[mt][nt] = MFMA16(pa, rb_c[nt * 2 + kk], acc[mt][nt]);
            }
        }

        // barrier2: drain OWN stage (vmcnt(12) leaves rb_n 8 + g_n 4 in flight),
        // after barrier the new kt tile is globally staged; also protects pl recycle.
        if (!last) {
            __builtin_amdgcn_sched_barrier(0);
            asm volatile("s_waitcnt vmcnt(12) lgkmcnt(0)");
            __builtin_amdgcn_s_barrier();
            __builtin_amdgcn_sched_barrier(0);
#pragma unroll
            for (int nt = 0; nt < 8; nt++) rb_c[nt] = rb_n[nt];
#pragma unroll
            for (int j = 0; j < 4; j++) g_c[j] = g_n[j];
        }
    }
#undef STAGE

    float* ob = out + (size_t)b * NT * DIM;
#pragma unroll
    for (int nt = 0; nt < 4; nt++) {
        int col = w * 64 + nt * 16 + lr;
#pragma unroll
        for (int mt = 0; mt < 4; mt++) {
            int rowb = t0 + mt * 16 + lg * 4;
#pragma unroll
            for (int r = 0; r < 4; r++)
                ob[(size_t)(rowb + r) * DIM + col] = acc[mt][nt][r];
        }
    }
}

// ---------------- launch ----------------

extern "C" void kernel_launch(void* const* d_in, const int* in_sizes, int n_in,
                              void* d_out, int out_size, void* d_ws, size_t ws_size,
                              hipStream_t stream) {
    const float* xc  = (const float*)d_in[0];
    const float* xt  = (const float*)d_in[1];
    const float* ri  = (const float*)d_in[2];
    const float* qw1 = (const float*)d_in[3];  const float* qb1 = (const float*)d_in[4];
    const float* qw2 = (const float*)d_in[5];  const float* qb2 = (const float*)d_in[6];
    const float* qw3 = (const float*)d_in[7];  const float* qb3 = (const float*)d_in[8];
    const float* kw1 = (const float*)d_in[9];  const float* kb1 = (const float*)d_in[10];
    const float* kw2 = (const float*)d_in[11]; const float* kb2 = (const float*)d_in[12];
    const float* kw3 = (const float*)d_in[13]; const float* kb3 = (const float*)d_in[14];

    if (ws_size < ((size_t)66 << 20)) return;  // need ~65.2 MB

    char* ws = (char*)d_ws;
    u16* h1q = (u16*)(ws);
    u16* h1k = (u16*)(ws + ((size_t)16 << 20));
    u16* q   = h1q;
    u16* kk  = h1k;
    u16* h2q = (u16*)(ws + ((size_t)32 << 20));
    u16* h2k = (u16*)(ws + ((size_t)48 << 20));
    u16* rt  = h2q;
    float2* gsb = (float2*)(ws + ((size_t)64 << 20));          // 256 KB
    u16* wbuf = (u16*)(ws + ((size_t)64 << 20) + (512 << 10)); // 640 KB
    u16* qw1t = wbuf;
    u16* qw2t = qw1t + 32768;
    u16* qw3t = qw2t + 65536;
    u16* kw1t = qw3t + 65536;
    u16* kw2t = kw1t + 32768;
    u16* kw3t = kw2t + 65536;

    // weights -> transposed bf16 (one launch)
    cvt_w_all<<<dim3(1280), 256, 0, stream>>>(qw1, qw2, qw3, kw1, kw2, kw3,
                                              qw1t, qw2t, qw3t, kw1t, kw2t, kw3t);

    // fused MLP (q and k paths in one launch via blockIdx.y)
    mlp_gemm<128, true,  true ><<<dim3(256, 2), 256, 0, stream>>>(xt, xc, qw1t, kw1t, qb1, kb1, h1q, h1k);
    mlp_gemm<256, true,  false><<<dim3(256, 2), 256, 0, stream>>>(h1q, h1k, qw2t, kw2t, qb2, kb2, h2q, h2k);
    mlp_gemm<256, false, false><<<dim3(256, 2), 256, 0, stream>>>(h2q, h2k, qw3t, kw3t, qb3, kb3, q, kk);

    // r_i -> rt
    cvt_rt_kernel<<<dim3(64, 8, BB), dim3(32, 8), 0, stream>>>(ri, rt);

    // pass 1: column stats
    stats_kernel<<<dim3(512), 256, 0, stream>>>(q, kk, gsb);

    // pass 2: attention output
    attn_kernel<<<dim3(512), 256, 0, stream>>>(q, kk, rt, gsb, (float*)d_out);
}

// Round 9
// 254.890 us; speedup vs baseline: 1.8484x; 1.3140x over previous
//
#include <hip/hip_runtime.h>

#define BB 16
#define NT 2048
#define NC 2048
#define DIM 256
#define INDIM 128

typedef unsigned short u16;
typedef __bf16 bfx8 __attribute__((ext_vector_type(8)));
typedef __bf16 bfx8a __attribute__((ext_vector_type(8), aligned(8)));
typedef float f32x4 __attribute__((ext_vector_type(4)));

__device__ __forceinline__ u16 f2bf(float f) {
    union { float f; unsigned u; } v; v.f = f;
    return (u16)((v.u + 0x7FFFu + ((v.u >> 16) & 1u)) >> 16);
}

#define MFMA16(a, b, c) __builtin_amdgcn_mfma_f32_16x16x32_bf16((a), (b), (c), 0, 0, 0)

// ---------------- converts ----------------

// all six weight transposes in ONE launch: w[K][256] fp32 -> wt[256][K] bf16
__global__ void cvt_w_all(const float* __restrict__ w0, const float* __restrict__ w1,
                          const float* __restrict__ w2, const float* __restrict__ w3,
                          const float* __restrict__ w4, const float* __restrict__ w5,
                          u16* __restrict__ o0, u16* __restrict__ o1, u16* __restrict__ o2,
                          u16* __restrict__ o3, u16* __restrict__ o4, u16* __restrict__ o5) {
    int bx = blockIdx.x;
    const float* src; u16* dst; int K, base;
    if (bx < 128)       { src = w0; dst = o0; K = 128; base = 0; }
    else if (bx < 384)  { src = w1; dst = o1; K = 256; base = 128; }
    else if (bx < 640)  { src = w2; dst = o2; K = 256; base = 384; }
    else if (bx < 768)  { src = w3; dst = o3; K = 128; base = 640; }
    else if (bx < 1024) { src = w4; dst = o4; K = 256; base = 768; }
    else                { src = w5; dst = o5; K = 256; base = 1024; }
    int idx = (bx - base) * 256 + threadIdx.x;
    int n = idx / K, k = idx - n * K;
    dst[idx] = f2bf(src[k * 256 + n]);
}

// r [B][NC][DIM] fp32 -> rt [B][DIM][NC] bf16
__global__ void cvt_rt_kernel(const float* __restrict__ r, u16* __restrict__ rt) {
    __shared__ u16 tile[32][33];
    int b = blockIdx.z;
    int c0 = blockIdx.x * 32, d0 = blockIdx.y * 32;
    int tx = threadIdx.x, ty = threadIdx.y; // (32, 8)
    const float* rb = r + (size_t)b * NC * DIM;
#pragma unroll
    for (int i = 0; i < 4; i++) {
        int c = c0 + ty + i * 8;
        tile[ty + i * 8][tx] = f2bf(rb[(size_t)c * DIM + d0 + tx]);
    }
    __syncthreads();
    u16* rtb = rt + (size_t)b * DIM * NC;
#pragma unroll
    for (int i = 0; i < 4; i++) {
        int d = d0 + ty + i * 8;
        rtb[(size_t)d * NC + c0 + tx] = tile[tx][ty + i * 8];
    }
}

// ---------------- fused 3-layer MLP: out = (relu(relu(x@W1+b1)@W2+b2))@W3+b3 ----------
// grid (512, 2): y=0 -> q path (x_target), y=1 -> k path (x_context). Block = 64 rows.
// h1/h2 never touch HBM: LDS 64 KB = h1[0,32K) + {xa,h2}[32K,64K) (h2 aliases dead xa).
// All LDS tiles XOR-swizzled (^((row&7)<<4)); weights [256][K] bf16 from L2.

__global__ __launch_bounds__(256) void mlp_fused(const float* __restrict__ xq, const float* __restrict__ xk,
                                                 const u16* __restrict__ W1q, const u16* __restrict__ W1k,
                                                 const float* __restrict__ b1q, const float* __restrict__ b1k,
                                                 const u16* __restrict__ W2q, const u16* __restrict__ W2k,
                                                 const float* __restrict__ b2q, const float* __restrict__ b2k,
                                                 const u16* __restrict__ W3q, const u16* __restrict__ W3k,
                                                 const float* __restrict__ b3q, const float* __restrict__ b3k,
                                                 u16* __restrict__ oq, u16* __restrict__ ok) {
    __shared__ __align__(16) char lds[65536];
    char* h1 = lds;            // [64][256] bf16, 512 B rows, swizzled
    char* xa = lds + 32768;    // [64][128] bf16, 256 B rows, swizzled
    char* h2 = lds + 32768;    // [64][256] bf16, 512 B rows, swizzled (after xa dead)

    int tid = threadIdx.x, lane = tid & 63, w = tid >> 6;
    int lr = lane & 15, lg = lane >> 4;
    int m0 = blockIdx.x * 64;
    bool isq = (blockIdx.y == 0);
    const float* X = (isq ? xq : xk) + (size_t)m0 * INDIM;
    const u16* W1 = isq ? W1q : W1k;  const float* b1 = isq ? b1q : b1k;
    const u16* W2 = isq ? W2q : W2k;  const float* b2 = isq ? b2q : b2k;
    const u16* W3 = isq ? W3q : W3k;  const float* b3 = isq ? b3q : b3k;
    u16* C = (isq ? oq : ok) + (size_t)m0 * 256;

    // stage x: 64x128 fp32 -> bf16 swizzled (4 chunks of 16 B per thread)
#pragma unroll
    for (int j = 0; j < 4; j++) {
        int bo = (j * 256 + tid) * 16;            // linear byte offset in 16 KB tile
        int row = bo >> 8;                        // 256 B rows
        int ir = bo & 255;
        const float* src = X + (size_t)row * INDIM + (ir >> 1);
        float4 f0 = *reinterpret_cast<const float4*>(src);
        float4 f1 = *reinterpret_cast<const float4*>(src + 4);
        union { u16 u[8]; uint4 v; } pk;
        {
            __bf16 h;
            h = (__bf16)f0.x; pk.u[0] = *(u16*)&h;
            h = (__bf16)f0.y; pk.u[1] = *(u16*)&h;
            h = (__bf16)f0.z; pk.u[2] = *(u16*)&h;
            h = (__bf16)f0.w; pk.u[3] = *(u16*)&h;
            h = (__bf16)f1.x; pk.u[4] = *(u16*)&h;
            h = (__bf16)f1.y; pk.u[5] = *(u16*)&h;
            h = (__bf16)f1.z; pk.u[6] = *(u16*)&h;
            h = (__bf16)f1.w; pk.u[7] = *(u16*)&h;
        }
        *reinterpret_cast<uint4*>(xa + row * 256 + (ir ^ ((row & 7) << 4))) = pk.v;
    }
    __syncthreads();

    int n0 = w * 64;
    const int key = (lr & 7) << 4;

    // ---- GEMM1: h1 = relu(x @ W1^T + b1), K=128 ----
    {
        f32x4 acc[4][4] = {};
#pragma unroll
        for (int ks = 0; ks < 4; ks++) {
            bfx8 b[4];
#pragma unroll
            for (int nt = 0; nt < 4; nt++)
                b[nt] = *reinterpret_cast<const bfx8*>(W1 + (size_t)(n0 + nt * 16 + lr) * 128 + ks * 32 + lg * 8);
#pragma unroll
            for (int mt = 0; mt < 4; mt++) {
                bfx8 a = *reinterpret_cast<const bfx8*>(xa + (mt * 16 + lr) * 256 + ((ks * 64 + lg * 16) ^ key));
#pragma unroll
                for (int nt = 0; nt < 4; nt++)
                    acc[mt][nt] = MFMA16(a, b[nt], acc[mt][nt]);
            }
        }
#pragma unroll
        for (int nt = 0; nt < 4; nt++) {
            int col = n0 + nt * 16 + lr;
            float bv = b1[col];
#pragma unroll
            for (int mt = 0; mt < 4; mt++) {
#pragma unroll
                for (int r = 0; r < 4; r++) {
                    int row = mt * 16 + lg * 4 + r;
                    float v = fmaxf(acc[mt][nt][r] + bv, 0.0f);
                    *(u16*)(h1 + row * 512 + ((col * 2) ^ ((row & 7) << 4))) = f2bf(v);
                }
            }
        }
    }
    __syncthreads();

    // ---- GEMM2: h2 = relu(h1 @ W2^T + b2), K=256 (h2 overwrites dead xa) ----
    {
        f32x4 acc[4][4] = {};
#pragma unroll
        for (int ks = 0; ks < 8; ks++) {
            bfx8 b[4];
#pragma unroll
            for (int nt = 0; nt < 4; nt++)
                b[nt] = *reinterpret_cast<const bfx8*>(W2 + (size_t)(n0 + nt * 16 + lr) * 256 + ks * 32 + lg * 8);
#pragma unroll
            for (int mt = 0; mt < 4; mt++) {
                bfx8 a = *reinterpret_cast<const bfx8*>(h1 + (mt * 16 + lr) * 512 + ((ks * 64 + lg * 16) ^ key));
#pragma unroll
                for (int nt = 0; nt < 4; nt++)
                    acc[mt][nt] = MFMA16(a, b[nt], acc[mt][nt]);
            }
        }
#pragma unroll
        for (int nt = 0; nt < 4; nt++) {
            int col = n0 + nt * 16 + lr;
            float bv = b2[col];
#pragma unroll
            for (int mt = 0; mt < 4; mt++) {
#pragma unroll
                for (int r = 0; r < 4; r++) {
                    int row = mt * 16 + lg * 4 + r;
                    float v = fmaxf(acc[mt][nt][r] + bv, 0.0f);
                    *(u16*)(h2 + row * 512 + ((col * 2) ^ ((row & 7) << 4))) = f2bf(v);
                }
            }
        }
    }
    __syncthreads();

    // ---- GEMM3: out = h2 @ W3^T + b3, K=256, write global bf16 ----
    {
        f32x4 acc[4][4] = {};
#pragma unroll
        for (int ks = 0; ks < 8; ks++) {
            bfx8 b[4];
#pragma unroll
            for (int nt = 0; nt < 4; nt++)
                b[nt] = *reinterpret_cast<const bfx8*>(W3 + (size_t)(n0 + nt * 16 + lr) * 256 + ks * 32 + lg * 8);
#pragma unroll
            for (int mt = 0; mt < 4; mt++) {
                bfx8 a = *reinterpret_cast<const bfx8*>(h2 + (mt * 16 + lr) * 512 + ((ks * 64 + lg * 16) ^ key));
#pragma unroll
                for (int nt = 0; nt < 4; nt++)
                    acc[mt][nt] = MFMA16(a, b[nt], acc[mt][nt]);
            }
        }
#pragma unroll
        for (int nt = 0; nt < 4; nt++) {
            int col = n0 + nt * 16 + lr;
            float bv = b3[col];
#pragma unroll
            for (int mt = 0; mt < 4; mt++) {
#pragma unroll
                for (int r = 0; r < 4; r++) {
                    int row = mt * 16 + lg * 4 + r;
                    C[(size_t)row * 256 + col] = f2bf(acc[mt][nt][r] + bv);
                }
            }
        }
    }
}

// ---------------- pass 1: column stats -> gs[c] = (m_c * log2e/16, 1/l_c) ----------------

__global__ __launch_bounds__(256) void stats_kernel(const u16* __restrict__ q,
                                                    const u16* __restrict__ k,
                                                    float2* __restrict__ gso) {
    int flat = blockIdx.x;
    int sw = (flat & 7) * 64 + (flat >> 3);   // bijective XCD swizzle: 2 batches/XCD
    int b = sw >> 5;
    int c0 = (sw & 31) * 64;
    int tid = threadIdx.x, lane = tid & 63, w = tid >> 6;
    int lr = lane & 15, lg = lane >> 4;
    const u16* qb = q + (size_t)b * NT * DIM;
    const u16* kb = k + (size_t)b * NC * DIM;
    const float A2 = 1.44269504f / 16.0f;    // log2e * scale

    bfx8 kf[4][8];
#pragma unroll
    for (int j = 0; j < 4; j++)
#pragma unroll
        for (int ks = 0; ks < 8; ks++)
            kf[j][ks] = *reinterpret_cast<const bfx8*>(kb + (size_t)(c0 + j * 16 + lr) * DIM + ks * 32 + lg * 8);

    float m_run[4], l_run[4];
#pragma unroll
    for (int j = 0; j < 4; j++) { m_run[j] = -1e30f; l_run[j] = 0.0f; }

    for (int ts = 0; ts < NT / 64; ts++) {
        int t0 = ts * 64 + w * 16;
        f32x4 acc[4] = {};
#pragma unroll
        for (int ks = 0; ks < 8; ks++) {
            bfx8 a = *reinterpret_cast<const bfx8*>(qb + (size_t)(t0 + lr) * DIM + ks * 32 + lg * 8);
#pragma unroll
            for (int j = 0; j < 4; j++)
                acc[j] = MFMA16(a, kf[j][ks], acc[j]);
        }
#pragma unroll
        for (int j = 0; j < 4; j++) {
            f32x4 a = acc[j];
            float mx = fmaxf(fmaxf(a[0], a[1]), fmaxf(a[2], a[3]));
            float mn = fmaxf(m_run[j], mx);
            float t = mn * A2;
            float sum = exp2f(fmaf(a[0], A2, -t)) + exp2f(fmaf(a[1], A2, -t)) +
                        exp2f(fmaf(a[2], A2, -t)) + exp2f(fmaf(a[3], A2, -t));
            l_run[j] = l_run[j] * exp2f(fmaf(m_run[j], A2, -t)) + sum;
            m_run[j] = mn;
        }
    }

    // intra-wave combine across the 4 lane-groups (rows), once
#pragma unroll
    for (int j = 0; j < 4; j++) {
        float m = m_run[j], l = l_run[j];
#pragma unroll
        for (int d = 16; d < 64; d <<= 1) {
            float mo = __shfl_xor(m, d);
            float lo = __shfl_xor(l, d);
            float mn = fmaxf(m, mo);
            l = l * exp2f((m - mn) * A2) + lo * exp2f((mo - mn) * A2);
            m = mn;
        }
        m_run[j] = m; l_run[j] = l;
    }

    __shared__ float sm[4][64], sl[4][64];
    if (lg == 0) {
#pragma unroll
        for (int j = 0; j < 4; j++) {
            sm[w][j * 16 + lr] = m_run[j];
            sl[w][j * 16 + lr] = l_run[j];
        }
    }
    __syncthreads();
    if (tid < 64) {
        float mf = sm[0][tid];
#pragma unroll
        for (int ww = 1; ww < 4; ww++) mf = fmaxf(mf, sm[ww][tid]);
        float lf = 0.0f;
#pragma unroll
        for (int ww = 0; ww < 4; ww++) lf += sl[ww][tid] * exp2f((sm[ww][tid] - mf) * A2);
        gso[(size_t)b * NC + c0 + tid] = make_float2(mf * A2, 1.0f / lf);
    }
}

// ---------------- pass 2: R4-proven pipelined attention (127 us) ----------
// t=64, c-step 32, 4 waves, kt dbuf 2x16K swizzled, pl[64][36], gs in LDS.
// Counted vmcnt: prologue vmcnt(12); in-loop lgkm0 barrier + vmcnt(4) barrier.

__global__ __launch_bounds__(256, 2) void attn_kernel(const u16* __restrict__ q,
                                                      const u16* __restrict__ k,
                                                      const u16* __restrict__ rt,
                                                      const float2* __restrict__ gsg_,
                                                      float* __restrict__ out) {
    int flat = blockIdx.x;
    int sw = (flat & 7) * 64 + (flat >> 3);   // each XCD -> 2 batches (k+rt fit L2)
    int b = sw >> 5;
    int t0 = (sw & 31) * 64;
    int tid = threadIdx.x, lane = tid & 63, w = tid >> 6;
    int lr = lane & 15, lg = lane >> 4;
    const u16* qb = q + (size_t)b * NT * DIM;
    const u16* kb = k + (size_t)b * NC * DIM;
    const u16* rtb = rt + (size_t)b * DIM * NC;

    __shared__ float2 gs[NC];                       // 16 KB
    __shared__ __align__(16) u16 kt[2][32 * 256];   // 2 x 16 KB, swizzled K tiles
    __shared__ u16 pl[64][36];                      // P tile, 72B rows

    {
        const float2* gsg = gsg_ + (size_t)b * NC;
        for (int i = tid; i < NC; i += 256) gs[i] = gsg[i];
    }
    __syncthreads();

#define STAGE(nb, cc) do {                                                          \
    const u16* ksrc_ = kb + (size_t)(cc) * DIM;                                     \
    _Pragma("unroll")                                                               \
    for (int i_ = 0; i_ < 4; i_++) {                                                \
        int off_ = ((w * 4 + i_) << 10) + (lane << 4);                              \
        int row_ = off_ >> 9;                                                       \
        int ss_  = ((off_ >> 4) & 31) ^ (row_ & 7);                                 \
        const u16* g_ = ksrc_ + row_ * DIM + ss_ * 8;                               \
        __builtin_amdgcn_global_load_lds(                                           \
            (const __attribute__((address_space(1))) void*)g_,                      \
            (__attribute__((address_space(3))) void*)(&kt[nb][(w * 4 + i_) << 9]),  \
            16, 0, 0);                                                              \
    }                                                                               \
} while (0)

    // prologue: stage tile 0, prefetch rb for tile 0, hoist q
    STAGE(0, 0);
    __builtin_amdgcn_sched_barrier(0);
    bfx8 rb_c[4], rb_n[4];
#pragma unroll
    for (int nt = 0; nt < 4; nt++)
        rb_c[nt] = *reinterpret_cast<const bfx8*>(rtb + (size_t)(w * 64 + nt * 16 + lr) * NC + lg * 8);
    bfx8 aq[8];
#pragma unroll
    for (int ks = 0; ks < 8; ks++)
        aq[ks] = *reinterpret_cast<const bfx8*>(qb + (size_t)(t0 + w * 16 + lr) * DIM + ks * 32 + lg * 8);
    __builtin_amdgcn_sched_barrier(0);
    asm volatile("s_waitcnt vmcnt(12)");   // drain 4 stage issues (12 newer: 4 rb + 8 aq)
    __builtin_amdgcn_s_barrier();
    __builtin_amdgcn_sched_barrier(0);

    const float A = 1.44269504f / 16.0f;   // log2e * (1/sqrt(256))
    const int key = lr & 7;
    f32x4 acc[4][4] = {};
    int cur = 0;

    for (int c0 = 0; c0 < NC; c0 += 32) {
        const bool last = (c0 + 32 >= NC);
        if (!last) STAGE(cur ^ 1, c0 + 32);
        __builtin_amdgcn_sched_barrier(0);
        if (!last) {
#pragma unroll
            for (int nt = 0; nt < 4; nt++)
                rb_n[nt] = *reinterpret_cast<const bfx8*>(rtb + (size_t)(w * 64 + nt * 16 + lr) * NC + (c0 + 32) + lg * 8);
        }

        // S phase: read swizzled kt[cur], 16 MFMAs
        f32x4 s[2] = {};
        {
            const char* kc = (const char*)&kt[cur][0];
#pragma unroll
            for (int ks = 0; ks < 8; ks++) {
                int slot = (ks << 2) | lg;
                bfx8 k0 = *reinterpret_cast<const bfx8*>(kc + (lr << 9) + (((slot ^ key)) << 4));
                bfx8 k1 = *reinterpret_cast<const bfx8*>(kc + ((16 + lr) << 9) + (((slot ^ key)) << 4));
                s[0] = MFMA16(aq[ks], k0, s[0]);
                s[1] = MFMA16(aq[ks], k1, s[1]);
            }
        }
        // P = exp2(S*A - m') * invl -> LDS
#pragma unroll
        for (int j = 0; j < 2; j++) {
            float2 g = gs[c0 + j * 16 + lr];
#pragma unroll
            for (int r = 0; r < 4; r++) {
                float p = exp2f(fmaf(s[j][r], A, -g.x)) * g.y;
                __bf16 h = (__bf16)p;
                pl[w * 16 + lg * 4 + r][j * 16 + lr] = *(u16*)&h;
            }
        }
        __builtin_amdgcn_sched_barrier(0);
        asm volatile("s_waitcnt lgkmcnt(0)");
        __builtin_amdgcn_s_barrier();
        __builtin_amdgcn_sched_barrier(0);

        // PV phase
#pragma unroll
        for (int mt = 0; mt < 4; mt++) {
            bfx8a pa = *reinterpret_cast<const bfx8a*>((const char*)pl + (mt * 16 + lr) * 72 + lg * 16);
#pragma unroll
            for (int nt = 0; nt < 4; nt++)
                acc[mt][nt] = MFMA16((bfx8)pa, rb_c[nt], acc[mt][nt]);
        }

        __builtin_amdgcn_sched_barrier(0);
        asm volatile("s_waitcnt vmcnt(4) lgkmcnt(0)");
        __builtin_amdgcn_s_barrier();
        __builtin_amdgcn_sched_barrier(0);

#pragma unroll
        for (int nt = 0; nt < 4; nt++) rb_c[nt] = rb_n[nt];
        cur ^= 1;
    }
#undef STAGE

    float* ob = out + (size_t)b * NT * DIM;
#pragma unroll
    for (int nt = 0; nt < 4; nt++) {
        int col = w * 64 + nt * 16 + lr;
#pragma unroll
        for (int mt = 0; mt < 4; mt++) {
            int rowb = t0 + mt * 16 + lg * 4;
#pragma unroll
            for (int r = 0; r < 4; r++)
                ob[(size_t)(rowb + r) * DIM + col] = acc[mt][nt][r];
        }
    }
}

// ---------------- launch ----------------

extern "C" void kernel_launch(void* const* d_in, const int* in_sizes, int n_in,
                              void* d_out, int out_size, void* d_ws, size_t ws_size,
                              hipStream_t stream) {
    const float* xc  = (const float*)d_in[0];
    const float* xt  = (const float*)d_in[1];
    const float* ri  = (const float*)d_in[2];
    const float* qw1 = (const float*)d_in[3];  const float* qb1 = (const float*)d_in[4];
    const float* qw2 = (const float*)d_in[5];  const float* qb2 = (const float*)d_in[6];
    const float* qw3 = (const float*)d_in[7];  const float* qb3 = (const float*)d_in[8];
    const float* kw1 = (const float*)d_in[9];  const float* kb1 = (const float*)d_in[10];
    const float* kw2 = (const float*)d_in[11]; const float* kb2 = (const float*)d_in[12];
    const float* kw3 = (const float*)d_in[13]; const float* kb3 = (const float*)d_in[14];

    if (ws_size < ((size_t)66 << 20)) return;  // need ~50 MB

    char* ws = (char*)d_ws;
    u16* q   = (u16*)(ws);                        // 16 MB q bf16
    u16* kk  = (u16*)(ws + ((size_t)16 << 20));   // 16 MB k bf16
    u16* rt  = (u16*)(ws + ((size_t)32 << 20));   // 16 MB rt bf16
    float2* gsb = (float2*)(ws + ((size_t)48 << 20));          // 256 KB col stats
    u16* wbuf = (u16*)(ws + ((size_t)48 << 20) + (512 << 10)); // 640 KB weights
    u16* qw1t = wbuf;
    u16* qw2t = qw1t + 32768;
    u16* qw3t = qw2t + 65536;
    u16* kw1t = qw3t + 65536;
    u16* kw2t = kw1t + 32768;
    u16* kw3t = kw2t + 65536;

    // weights -> transposed bf16 (one launch)
    cvt_w_all<<<dim3(1280), 256, 0, stream>>>(qw1, qw2, qw3, kw1, kw2, kw3,
                                              qw1t, qw2t, qw3t, kw1t, kw2t, kw3t);

    // fused 3-layer MLP, both paths, h1/h2 in LDS only
    mlp_fused<<<dim3(512, 2), 256, 0, stream>>>(xt, xc,
                                                qw1t, kw1t, qb1, kb1,
                                                qw2t, kw2t, qb2, kb2,
                                                qw3t, kw3t, qb3, kb3,
                                                q, kk);

    // r_i -> rt
    cvt_rt_kernel<<<dim3(64, 8, BB), dim3(32, 8), 0, stream>>>(ri, rt);

    // pass 1: column stats
    stats_kernel<<<dim3(512), 256, 0, stream>>>(q, kk, gsb);

    // pass 2: attention output
    attn_kernel<<<dim3(512), 256, 0, stream>>>(q, kk, rt, gsb, (float*)d_out);
}